// Round 5
// baseline (30.877 us; speedup 1.0000x reference)
//
#include <hip/hip_runtime.h>
#include <math.h>

// Geometry fixed by reference: B=4, C=3, D=H=W=64.
#define VOXB 262144              // 64^3
#define NVOX 1048576             // 4 * VOXB
#define NACC 14
#define PITCH 65                 // LDS pitch: bank=(lane+j)%32 -> 2-way = free
#define NBLK 512                 // 2 blocks per slab/plane
#define D2CLAMP 16383.0f         // 14-bit clamp; genuine W+D max = 2*63^2 = 7938,
                                 // genuine 3D max = 3*63^2 = 11907 < 16383, so a
                                 // clamped "inf" never beats a real candidate.

// ---------------------------------------------------------------------------
// Squared distance (float) from position i to nearest set bit of 64b mask.
// Empty mask -> 1e6 (acts as inf; clamped to 16383 on pack).
// ---------------------------------------------------------------------------
__device__ __forceinline__ float n2side(unsigned long long m, int i) {
    unsigned long long right = m >> i;
    unsigned long long left  = m << (63 - i);
    int dr = right ? __builtin_ctzll(right) : 1000;
    int dl = left  ? __builtin_clzll(left)  : 1000;
    int d  = dr < dl ? dr : dl;
    return (float)(d * d);
}

// ---------------------------------------------------------------------------
// Kernel A: 2 blocks per (b,h) slab [d][w]. Phase 1: W-pass via ballot for all
// 64 d-rows; pack (wpos2 | wneg2<<14 | t<<28 | s<<30) into transposed LDS
// T[w][d]. Phase 2: D-axis radius spiral (4 rows/wave, uniform early exit).
// Output voxel (b,d,h,w) gets W+D distances + t,s bits (scattered 256B writes).
// ---------------------------------------------------------------------------
__global__ __launch_bounds__(512) void edt_wd(const int* __restrict__ targets,
                                              const int* __restrict__ skel,
                                              unsigned int* __restrict__ d2) {
    __shared__ unsigned int T[64 * PITCH];   // T[w][d]
    int slab = blockIdx.x >> 1;              // b*64 + h
    int half = blockIdx.x & 1;
    int b = slab >> 6, h = slab & 63;
    int base = b * VOXB + h * 64;            // + d*4096 + w
    int wv   = threadIdx.x >> 6;
    int lane = threadIdx.x & 63;             // = w

#pragma unroll
    for (int rt = 0; rt < 8; ++rt) {
        int d = wv * 8 + rt;
        int off = base + d * 4096 + lane;
        int tv = targets[off];
        int sv = skel[off];
        unsigned long long m = __ballot(tv == 1);
        unsigned int p = (unsigned int)fminf(n2side(m, lane), D2CLAMP);
        unsigned int n = (unsigned int)fminf(n2side(~m, lane), D2CLAMP);
        T[lane * PITCH + d] = p | (n << 14) | ((unsigned int)tv << 28)
                                | ((unsigned int)sv << 30);
    }
    __syncthreads();

    int dbase = half * 32 + wv * 4;
    float mp[4], mn[4];
    unsigned int ts[4];
#pragma unroll
    for (int rt = 0; rt < 4; ++rt) {
        unsigned int v = T[lane * PITCH + dbase + rt];
        mp[rt] = (float)(v & 16383u);
        mn[rt] = (float)((v >> 14) & 16383u);
        ts[rt] = v >> 28;
    }
    for (int r = 1; r < 64; ++r) {
        float rr = (float)(r * r);
        unsigned int vl[4], vr[4];
#pragma unroll
        for (int rt = 0; rt < 4; ++rt) {
            int d = dbase + rt;
            int jl = d - r; jl = jl < 0 ? 0 : jl;
            int jr = d + r; jr = jr > 63 ? 63 : jr;
            vl[rt] = T[lane * PITCH + jl];
            vr[rt] = T[lane * PITCH + jr];
        }
        bool ok = true;
        float thr = (float)((r + 1) * (r + 1));
#pragma unroll
        for (int rt = 0; rt < 4; ++rt) {
            mp[rt] = fminf(mp[rt], fminf((float)(vl[rt] & 16383u),
                                         (float)(vr[rt] & 16383u)) + rr);
            mn[rt] = fminf(mn[rt], fminf((float)((vl[rt] >> 14) & 16383u),
                                         (float)((vr[rt] >> 14) & 16383u)) + rr);
            ok = ok && (mp[rt] <= thr) && (mn[rt] <= thr);
        }
        if (__all(ok)) break;                // remaining candidates >= (r+1)^2
    }
#pragma unroll
    for (int rt = 0; rt < 4; ++rt) {
        unsigned int p = (unsigned int)fminf(mp[rt], D2CLAMP);
        unsigned int n = (unsigned int)fminf(mn[rt], D2CLAMP);
        d2[base + (dbase + rt) * 4096 + lane] = p | (n << 14) | (ts[rt] << 28);
    }
}

// ---------------------------------------------------------------------------
// Per-voxel pointwise math + accumulation.
// ---------------------------------------------------------------------------
__device__ __forceinline__ void vox_accum(float l0, float l1, float l2,
                                          int t, int s, float sd, float* acc) {
    float m  = fmaxf(l0, fmaxf(l1, l2));
    float e0 = __expf(l0 - m), e1 = __expf(l1 - m), e2 = __expf(l2 - m);
    float sum = e0 + e1 + e2;
    float inv = 1.0f / sum;
    float p0 = e0 * inv, p1 = e1 * inv, p2 = e2 * inv;
    float logs = __logf(sum);
    float pt, lpt, alpha;
    if (t == 0)      { pt = p0; lpt = l0 - m - logs; alpha = 0.3f; }
    else if (t == 1) { pt = p1; lpt = l1 - m - logs; alpha = 3.0f; }
    else             { pt = p2; lpt = l2 - m - logs; alpha = 0.3f; }
    float om = 1.0f - pt;
    acc[0] += alpha * om * om * lpt;
    acc[1] += (t == 0) ? p0 : 0.f;
    acc[2] += (t == 1) ? p1 : 0.f;
    acc[3] += (t == 2) ? p2 : 0.f;
    acc[4] += p0; acc[5] += p1; acc[6] += p2;
    acc[7] += (t == 0) ? 1.f : 0.f;
    acc[8] += (t == 1) ? 1.f : 0.f;
    acc[9] += (t == 2) ? 1.f : 0.f;
    float fs = (float)s;
    acc[10] += p1 * fs;
    acc[11] += fs;
    acc[12] += p1;
    acc[13] += p1 * sd;
}

// ---------------------------------------------------------------------------
// Kernel B: 2 blocks per (b,d) plane [h][w]. Contiguous 16 KB tile read
// (transposed into LDS), H-axis spiral (4 rows/wave), fused pointwise with
// CONTIGUOUS logits reads; t,s ride in the packed tile. Block partials out.
// ---------------------------------------------------------------------------
__global__ __launch_bounds__(512) void edt_h_reduce(
        const float* __restrict__ logits, const unsigned int* __restrict__ d2,
        float* __restrict__ partials) {
    __shared__ unsigned int T[64 * PITCH];   // T[w][h]
    __shared__ float red[8][NACC];
    int plane = blockIdx.x >> 1;             // b*64 + d
    int half  = blockIdx.x & 1;
    int b = plane >> 6, d = plane & 63;
    int pbase = b * VOXB + d * 4096;         // + h*64 + w
    int t = threadIdx.x;
    int wv = t >> 6, lane = t & 63;          // lane = w
    int hbase = half * 32 + wv * 4;

    // Contiguous 16 KB tile load, transposed into LDS.
#pragma unroll
    for (int k = 0; k < 2; ++k) {
        int f  = k * 512 + t;                // 0..1023 uint4 groups
        int h  = f >> 4;
        int w0 = (f & 15) * 4;
        uint4 q = *reinterpret_cast<const uint4*>(d2 + pbase + h * 64 + w0);
        T[(w0 + 0) * PITCH + h] = q.x;
        T[(w0 + 1) * PITCH + h] = q.y;
        T[(w0 + 2) * PITCH + h] = q.z;
        T[(w0 + 3) * PITCH + h] = q.w;
    }

    // Prefetch logits (contiguous 256B runs; in flight during sync + spiral).
    float l0[4], l1[4], l2[4];
    size_t lbase = (size_t)b * (3 * VOXB) + d * 4096;
#pragma unroll
    for (int rt = 0; rt < 4; ++rt) {
        size_t lb = lbase + (hbase + rt) * 64 + lane;
        l0[rt] = logits[lb];
        l1[rt] = logits[lb + VOXB];
        l2[rt] = logits[lb + 2 * VOXB];
    }
    __syncthreads();

    // H-axis spiral, 4 rows interleaved.
    float mp[4], mn[4];
    unsigned int ts[4];
#pragma unroll
    for (int rt = 0; rt < 4; ++rt) {
        unsigned int v = T[lane * PITCH + hbase + rt];
        mp[rt] = (float)(v & 16383u);
        mn[rt] = (float)((v >> 14) & 16383u);
        ts[rt] = v >> 28;
    }
    for (int r = 1; r < 64; ++r) {
        float rr = (float)(r * r);
        unsigned int vl[4], vr[4];
#pragma unroll
        for (int rt = 0; rt < 4; ++rt) {
            int h = hbase + rt;
            int jl = h - r; jl = jl < 0 ? 0 : jl;
            int jr = h + r; jr = jr > 63 ? 63 : jr;
            vl[rt] = T[lane * PITCH + jl];
            vr[rt] = T[lane * PITCH + jr];
        }
        bool ok = true;
        float thr = (float)((r + 1) * (r + 1));
#pragma unroll
        for (int rt = 0; rt < 4; ++rt) {
            mp[rt] = fminf(mp[rt], fminf((float)(vl[rt] & 16383u),
                                         (float)(vr[rt] & 16383u)) + rr);
            mn[rt] = fminf(mn[rt], fminf((float)((vl[rt] >> 14) & 16383u),
                                         (float)((vr[rt] >> 14) & 16383u)) + rr);
            ok = ok && (mp[rt] <= thr) && (mn[rt] <= thr);
        }
        if (__all(ok)) break;
    }

    // Pointwise + per-thread accumulation.
    float acc[NACC];
#pragma unroll
    for (int k = 0; k < NACC; ++k) acc[k] = 0.f;
#pragma unroll
    for (int rt = 0; rt < 4; ++rt) {
        float sd = sqrtf(mp[rt]) - sqrtf(mn[rt]);
        vox_accum(l0[rt], l1[rt], l2[rt], (int)(ts[rt] & 3u),
                  (int)(ts[rt] >> 2), sd, acc);
    }

    // Wave reduce -> LDS -> block partials.
#pragma unroll
    for (int k = 0; k < NACC; ++k) {
        float v = acc[k];
#pragma unroll
        for (int off = 32; off; off >>= 1) v += __shfl_down(v, off, 64);
        if (lane == 0) red[wv][k] = v;
    }
    __syncthreads();
    if (t < NACC) {
        float v = 0.f;
#pragma unroll
        for (int q = 0; q < 8; ++q) v += red[q][t];
        partials[t * NBLK + blockIdx.x] = v;
    }
}

// ---------------------------------------------------------------------------
// Kernel C: final reduction (1 block, 256 threads). Batch b owns blocks
// [b*128, b*128+128); wave w reduces batch w. Thread 0 assembles in f64.
// ---------------------------------------------------------------------------
__global__ __launch_bounds__(256) void final_reduce(
        const float* __restrict__ partials, float* __restrict__ out) {
    __shared__ float sb[NACC][4];
    int w = threadIdx.x >> 6, lane = threadIdx.x & 63;
#pragma unroll
    for (int k = 0; k < NACC; ++k) {
        const float* p = partials + k * NBLK + w * 128;
        float v = p[lane] + p[lane + 64];
#pragma unroll
        for (int off = 32; off; off >>= 1) v += __shfl_down(v, off, 64);
        if (lane == 0) sb[k][w] = v;
    }
    __syncthreads();
    if (threadIdx.x == 0) {
        double S[NACC];
#pragma unroll
        for (int k = 0; k < NACC; ++k)
            S[k] = (double)sb[k][0] + sb[k][1] + sb[k][2] + sb[k][3];
        const double W[3] = {0.3, 3.0, 0.3};
        double focal = -S[0] / (double)NVOX;
        double dice = 0.0;
        for (int c = 0; c < 3; ++c)
            dice += W[c] * (1.0 - (2.0 * S[1 + c] + 1.0) /
                                  (S[4 + c] + S[7 + c] + 1.0));
        double lfd = focal + dice / 3.6;
        double lsk = 1.0 - (S[10] + 1.0) / (S[11] + 1.0);
        double lb = 0.0;
        for (int bb = 0; bb < 4; ++bb) {
            double gs = sb[8][bb];
            double ps = sb[12][bb];
            double tm = sb[13][bb];
            double per;
            if (gs == 0.0)               per = ps / (double)VOXB;
            else if (gs == (double)VOXB) per = 1.0 - ps / (double)VOXB;
            else                         per = tm / (double)VOXB;
            lb += per;
        }
        lb *= 0.25;
        double total = 0.3 * lfd + 0.3 * lsk + 0.2 * lb;
        out[0] = (float)total;
        out[1] = (float)lfd;
        out[2] = (float)lsk;
        out[3] = (float)lb;
    }
}

// ---------------------------------------------------------------------------
extern "C" void kernel_launch(void* const* d_in, const int* in_sizes, int n_in,
                              void* d_out, int out_size, void* d_ws, size_t ws_size,
                              hipStream_t stream) {
    const float* logits  = (const float*)d_in[0];
    const int*   targets = (const int*)d_in[1];
    const int*   skel    = (const int*)d_in[2];
    unsigned int* d2     = (unsigned int*)d_ws;            // NVOX uints (4 MB)
    float* partials      = (float*)(d2 + NVOX);            // NACC*NBLK floats
    float* out = (float*)d_out;

    edt_wd<<<NBLK, 512, 0, stream>>>(targets, skel, d2);
    edt_h_reduce<<<NBLK, 512, 0, stream>>>(logits, d2, partials);
    final_reduce<<<1, 256, 0, stream>>>(partials, out);
}